// Round 15
// baseline (1035.648 us; speedup 1.0000x reference)
//
#include <hip/hip_runtime.h>

#define DD 256   // feature dim
#define N1 512
#define N2 512
#define BB 4

// Packed fp32: gfx950 (gfx90a+) PackedFP32Ops; the compiler selects
// v_pk_{add,mul,fma}_f32 from <2 x float> vector IR.
typedef float f2 __attribute__((ext_vector_type(2)));

// ---------------------------------------------------------------------------
// Kernel 1: projection GEMMs. R2 math/tiling verbatim (32x64 tile / 256
// threads / 2x4 packed register blocking, 512 blocks = 2/CU), upgraded with
// the R11-proven STATIC-NAMED LDS double-buffer: 8 barriers instead of 16.
// Runtime-indexed dbuf remains condemned (R1/R9 scratch disaster).
// Hazard audit: every write to buffer P is after a barrier that post-dates
// all threads' compute on P.
// ---------------------------------------------------------------------------
__global__ __launch_bounds__(256) void proj_kernel(
    const float* __restrict__ x, const float* __restrict__ y,
    const float* __restrict__ W1, const float* __restrict__ b1,
    float* __restrict__ xp, float* __restrict__ yp)
{
    const int which = blockIdx.z;
    const float* __restrict__ A  = which ? y : x;
    const float* __restrict__ Bw = W1 + which * DD * DD;
    float* __restrict__ outp = which ? yp : xp;

    __shared__ float AsA[32 * 36];   // As[k][m] (transposed), stride 36
    __shared__ float AsB[32 * 36];
    __shared__ float BsA[32 * 68];   // Bs[k][n], stride 68
    __shared__ float BsB[32 * 68];

    const int tid = threadIdx.x;
    const int tx = tid & 15, ty = tid >> 4;
    const int mBase = blockIdx.x * 32;
    const int nBase = blockIdx.y * 64;

    const float4* A4 = (const float4*)A;
    const float4* B4 = (const float4*)Bw;

    const int ar = tid >> 3;       // 0..31  A row (m)
    const int ac = tid & 7;        // 0..7   A float4 col (k/4)
    const int br = tid >> 4;       // 0..15  B k-row (and +16)
    const int bc = tid & 15;       // 0..15  B float4 col (n/4)

    float4 pa, pb0, pb1;
    f2 accl[2] = {}, acch[2] = {};

#define P_LOAD(KC)                                                      \
    pa  = A4[(mBase + ar) * 64 + (KC) * 8 + ac];                        \
    pb0 = B4[((KC) * 32 + br) * 64 + (nBase >> 2) + bc];                \
    pb1 = B4[((KC) * 32 + br + 16) * 64 + (nBase >> 2) + bc];

#define P_WRITE(AS, BS)                                                 \
    {                                                                   \
        float av[4] = {pa.x, pa.y, pa.z, pa.w};                         \
        _Pragma("unroll")                                               \
        for (int q = 0; q < 4; ++q) AS[(ac * 4 + q) * 36 + ar] = av[q]; \
        *(float4*)&BS[br * 68 + bc * 4] = pb0;                          \
        *(float4*)&BS[(br + 16) * 68 + bc * 4] = pb1;                   \
    }

#define P_COMP(AS, BS)                                                  \
    _Pragma("unroll")                                                   \
    for (int k = 0; k < 32; ++k) {                                      \
        f2 a = *(const f2*)&AS[k * 36 + ty * 2];                        \
        float4 bv = *(const float4*)&BS[k * 68 + tx * 4];               \
        f2 blo = {bv.x, bv.y};                                          \
        f2 bhi = {bv.z, bv.w};                                          \
        f2 a0 = {a.x, a.x};                                             \
        f2 a1 = {a.y, a.y};                                             \
        accl[0] = __builtin_elementwise_fma(a0, blo, accl[0]);          \
        acch[0] = __builtin_elementwise_fma(a0, bhi, acch[0]);          \
        accl[1] = __builtin_elementwise_fma(a1, blo, accl[1]);          \
        acch[1] = __builtin_elementwise_fma(a1, bhi, acch[1]);          \
    }

    P_LOAD(0) P_WRITE(AsA, BsA) __syncthreads();
    P_LOAD(1) P_COMP(AsA, BsA) P_WRITE(AsB, BsB) __syncthreads();
    P_LOAD(2) P_COMP(AsB, BsB) P_WRITE(AsA, BsA) __syncthreads();
    P_LOAD(3) P_COMP(AsA, BsA) P_WRITE(AsB, BsB) __syncthreads();
    P_LOAD(4) P_COMP(AsB, BsB) P_WRITE(AsA, BsA) __syncthreads();
    P_LOAD(5) P_COMP(AsA, BsA) P_WRITE(AsB, BsB) __syncthreads();
    P_LOAD(6) P_COMP(AsB, BsB) P_WRITE(AsA, BsA) __syncthreads();
    P_LOAD(7) P_COMP(AsA, BsA) P_WRITE(AsB, BsB) __syncthreads();
    P_COMP(AsB, BsB)

#undef P_LOAD
#undef P_WRITE
#undef P_COMP

    float4 bias = make_float4(0.f, 0.f, 0.f, 0.f);
    if (which == 0) bias = *((const float4*)b1 + (nBase >> 2) + tx);
    #pragma unroll
    for (int i = 0; i < 2; ++i) {
        float4 ov;
        ov.x = accl[i].x + bias.x;
        ov.y = accl[i].y + bias.y;
        ov.z = acch[i].x + bias.z;
        ov.w = acch[i].y + bias.w;
        ((float4*)outp)[(mBase + ty * 2 + i) * (DD / 4) + (nBase >> 2) + tx] = ov;
    }
}

// ---------------------------------------------------------------------------
// Kernel 2: o[b,n,m] = sum_d gelu(xp[b,n,d] + yp[b,m,d]) * W2[d] + b2
// R15: ONE-BARRIER cross. Synthesis of R12 (52.2: 5 barriers, all-staged),
// R13 (97.7: no LDS -- y-scatter kills, x-broadcast fine), R14 (LDS-read
// count doesn't matter): LDS's only irreplaceable job is deduplicating the
// y-scatter, and the block's full y-panel is just 32 rows x 256 d = 32 KB.
// So stage ys ONCE (full depth, single buffer, stride 260), one barrier,
// then pure compute: per c4, 1 ds_read_b128 (yr) + 2 broadcast global loads
// (x rows; block x-tile = 32 KB = L1-resident) + s_load (W2).
// One c4-iter = 80 cyc VALU >> L1 latency; 4 blocks/CU (LDS 33280 B) keeps
// 32 waves/CU TLP. No chunk loop, no write drains, no dbuf.
// Per-thread math and summation order BIT-IDENTICAL to R12 -> absmax
// must stay 0.00390625.
// Banks: ys writes (4sr+4sc)%32 = R12-proven pattern (0 conflicts);
// ys reads 2-way (free); x reads broadcast.
// TRIPWIRE: dur >= 52 & VALUBusy < 70 => x-latency-bound => revert to R12.
// ---------------------------------------------------------------------------
#define GC1  0.79687960f
#define GC3  (-0.13053245f)
#define GC5  0.018104800f
#define GC7  (-0.0017319756f)
#define GC9  1.05671e-4f
#define GC11 (-3.64829e-6f)
#define GC13 5.37117e-8f

__global__ __launch_bounds__(512, 4) void cross_kernel(
    const float* __restrict__ xp, const float* __restrict__ yp,
    const float* __restrict__ W2, const float* __restrict__ b2,
    float* __restrict__ o)
{
    __shared__ float ys[32 * 260];   // 32 m-rows x full 256 d, stride 260

    const int tid   = threadIdx.x;
    const int b     = blockIdx.z;
    const int mBase = blockIdx.x * 32;
    const int nBase = blockIdx.y * 32;
    const int tx = tid & 31;       // m col (single)
    const int ty = tid >> 5;       // 0..15: n rows ty, ty+16

    const float4* __restrict__ xr0p =
        (const float4*)xp + (size_t)(b * N1 + nBase + ty) * (DD / 4);
    const float4* __restrict__ xr1p = xr0p + 16 * (DD / 4);
    const float4* __restrict__ yp4 =
        (const float4*)yp + (size_t)(b * N2 + mBase) * (DD / 4);
    const float4* __restrict__ W2v = (const float4*)W2;

    // stage the full 256-d y-panel once: 32 rows x 64 f4, 4 f4/thread
    const int sr = tid >> 4;            // 0..31  row
    const int sc = tid & 15;            // 0..15  f4 col (and +16,+32,+48)

    float4 py0 = yp4[sr * 64 + sc];
    float4 py1 = yp4[sr * 64 + sc + 16];
    float4 py2 = yp4[sr * 64 + sc + 32];
    float4 py3 = yp4[sr * 64 + sc + 48];
    *(float4*)&ys[sr * 260 + sc * 4]        = py0;
    *(float4*)&ys[sr * 260 + (sc + 16) * 4] = py1;
    *(float4*)&ys[sr * 260 + (sc + 32) * 4] = py2;
    *(float4*)&ys[sr * 260 + (sc + 48) * 4] = py3;
    __syncthreads();                     // the ONLY barrier

    f2 accA[2] = {};   // lo-half accumulators (i = n-row 0/1)
    f2 accB[2] = {};   // hi-half accumulators

    #pragma unroll 16
    for (int c4 = 0; c4 < 64; ++c4) {
        float4 wv  = W2v[c4];           // uniform -> s_load
        f2 wlo = {wv.x, wv.y};
        f2 whi = {wv.z, wv.w};
        float4 yr  = *(const float4*)&ys[tx * 260 + c4 * 4];
        f2 ylo = {yr.x, yr.y};
        f2 yhi = {yr.z, yr.w};
        float4 xr0 = xr0p[c4];          // 2 addrs/wave: broadcast, L1-hit
        float4 xr1 = xr1p[c4];
        #pragma unroll
        for (int i = 0; i < 2; ++i) {
            float4 xr = i ? xr1 : xr0;
            f2 xlo = {xr.x, xr.y};
            f2 xhi = {xr.z, xr.w};
            f2 hlo = xlo + ylo;
            f2 hhi = xhi + yhi;
            f2 ulo = hlo * hlo;
            f2 uhi = hhi * hhi;
            // q = Q(u): erf(h/sqrt2) = h*Q(h^2), Horner deg-6 in u
            f2 qlo = __builtin_elementwise_fma(ulo, (f2)GC13, (f2)GC11);
            f2 qhi = __builtin_elementwise_fma(uhi, (f2)GC13, (f2)GC11);
            qlo = __builtin_elementwise_fma(qlo, ulo, (f2)GC9);
            qhi = __builtin_elementwise_fma(qhi, uhi, (f2)GC9);
            qlo = __builtin_elementwise_fma(qlo, ulo, (f2)GC7);
            qhi = __builtin_elementwise_fma(qhi, uhi, (f2)GC7);
            qlo = __builtin_elementwise_fma(qlo, ulo, (f2)GC5);
            qhi = __builtin_elementwise_fma(qhi, uhi, (f2)GC5);
            qlo = __builtin_elementwise_fma(qlo, ulo, (f2)GC3);
            qhi = __builtin_elementwise_fma(qhi, uhi, (f2)GC3);
            qlo = __builtin_elementwise_fma(qlo, ulo, (f2)GC1);
            qhi = __builtin_elementwise_fma(qhi, uhi, (f2)GC1);
            // gelu = 0.5*(h + u*q); the 0.5 is applied in the epilogue
            f2 slo = __builtin_elementwise_fma(ulo, qlo, hlo);
            f2 shi = __builtin_elementwise_fma(uhi, qhi, hhi);
            accA[i] = __builtin_elementwise_fma(slo, wlo, accA[i]);
            accB[i] = __builtin_elementwise_fma(shi, whi, accB[i]);
        }
    }

    const float bias2 = b2[0];
    const size_t base = ((size_t)(b * N1 + nBase)) * N2 + mBase;
    #pragma unroll
    for (int i = 0; i < 2; ++i) {
        o[base + (size_t)(ty + 16 * i) * N2 + tx] =
            0.5f * (accA[i].x + accA[i].y + accB[i].x + accB[i].y) + bias2;
    }
}

extern "C" void kernel_launch(void* const* d_in, const int* in_sizes, int n_in,
                              void* d_out, int out_size, void* d_ws, size_t ws_size,
                              hipStream_t stream)
{
    const float* x  = (const float*)d_in[0];
    const float* y  = (const float*)d_in[1];
    const float* W1 = (const float*)d_in[2];
    const float* b1 = (const float*)d_in[3];
    const float* W2 = (const float*)d_in[4];
    const float* b2 = (const float*)d_in[5];
    float* o  = (float*)d_out;
    float* xp = (float*)d_ws;                 // 2048*256 floats = 2 MB
    float* yp = xp + (BB * N1) * DD;          // next 2 MB

    dim3 g1(64, 4, 2);               // (M/32, N/64, which) = 512 blocks
    proj_kernel<<<g1, 256, 0, stream>>>(x, y, W1, b1, xp, yp);

    dim3 g2(N2 / 32, N1 / 32, BB);   // 16 x 16 x 4 = 1024 eight-wave blocks
    cross_kernel<<<g2, 512, 0, stream>>>(xp, yp, W2, b2, o);
}

// Round 16
// 129.070 us; speedup vs baseline: 8.0239x; 8.0239x over previous
//
#include <hip/hip_runtime.h>

#define DD 256   // feature dim
#define N1 512
#define N2 512
#define BB 4

// Packed fp32: gfx950 (gfx90a+) PackedFP32Ops; the compiler selects
// v_pk_{add,mul,fma}_f32 from <2 x float> vector IR.
typedef float f2 __attribute__((ext_vector_type(2)));

// ---------------------------------------------------------------------------
// Kernel 1: projection GEMMs. R2 version VERBATIM and now FROZEN: 32x64 tile
// / 256 threads / 2x4 packed register blocking, K-chunks of 32, register-
// prefetch double buffering, 512 blocks = 2/CU.
// R15's macro-unrolled static-dbuf rewrite exploded (VGPR 256, 393K bank
// conflicts, 1.08 GB scratch, 940 us): ~300 straight-line unrolled K-iters
// overwhelm the register allocator. Loop-form + 2 buffers is the proven
// shape; do not touch proj again.
// ---------------------------------------------------------------------------
__global__ __launch_bounds__(256) void proj_kernel(
    const float* __restrict__ x, const float* __restrict__ y,
    const float* __restrict__ W1, const float* __restrict__ b1,
    float* __restrict__ xp, float* __restrict__ yp)
{
    const int which = blockIdx.z;
    const float* __restrict__ A  = which ? y : x;
    const float* __restrict__ Bw = W1 + which * DD * DD;
    float* __restrict__ outp = which ? yp : xp;

    __shared__ float As[32 * 36];   // As[k][m] (transposed), stride 36
    __shared__ float Bs[32 * 68];   // Bs[k][n], stride 68

    const int tid = threadIdx.x;
    const int tx = tid & 15, ty = tid >> 4;
    const int mBase = blockIdx.x * 32;
    const int nBase = blockIdx.y * 64;

    const float4* A4 = (const float4*)A;
    const float4* B4 = (const float4*)Bw;

    const int ar = tid >> 3;       // 0..31  A row (m)
    const int ac = tid & 7;        // 0..7   A float4 col (k/4)
    const int br = tid >> 4;       // 0..15  B k-row (and +16)
    const int bc = tid & 15;       // 0..15  B float4 col (n/4)

    float4 pa, pb0, pb1;
    pa  = A4[(mBase + ar) * 64 + 0 * 8 + ac];
    pb0 = B4[(0 * 32 + br) * 64 + (nBase >> 2) + bc];
    pb1 = B4[(0 * 32 + br + 16) * 64 + (nBase >> 2) + bc];

    // acc[i] split into lo/hi f2 halves of the 4-wide n block -> v_pk_fma
    f2 accl[2] = {}, acch[2] = {};

    for (int kc = 0; kc < 8; ++kc) {
        __syncthreads();
        {
            float av[4] = {pa.x, pa.y, pa.z, pa.w};
            #pragma unroll
            for (int q = 0; q < 4; ++q) As[(ac * 4 + q) * 36 + ar] = av[q];
            *(float4*)&Bs[br * 68 + bc * 4] = pb0;
            *(float4*)&Bs[(br + 16) * 68 + bc * 4] = pb1;
        }
        __syncthreads();
        if (kc < 7) {
            pa  = A4[(mBase + ar) * 64 + (kc + 1) * 8 + ac];
            pb0 = B4[((kc + 1) * 32 + br) * 64 + (nBase >> 2) + bc];
            pb1 = B4[((kc + 1) * 32 + br + 16) * 64 + (nBase >> 2) + bc];
        }
        #pragma unroll
        for (int k = 0; k < 32; ++k) {
            f2 a = *(const f2*)&As[k * 36 + ty * 2];
            float4 b = *(const float4*)&Bs[k * 68 + tx * 4];
            f2 blo = {b.x, b.y};
            f2 bhi = {b.z, b.w};
            f2 a0 = {a.x, a.x};     // splat -> op_sel, free in VOP3P
            f2 a1 = {a.y, a.y};
            accl[0] = __builtin_elementwise_fma(a0, blo, accl[0]);
            acch[0] = __builtin_elementwise_fma(a0, bhi, acch[0]);
            accl[1] = __builtin_elementwise_fma(a1, blo, accl[1]);
            acch[1] = __builtin_elementwise_fma(a1, bhi, acch[1]);
        }
    }

    float4 bias = make_float4(0.f, 0.f, 0.f, 0.f);
    if (which == 0) bias = *((const float4*)b1 + (nBase >> 2) + tx);
    #pragma unroll
    for (int i = 0; i < 2; ++i) {
        float4 o;
        o.x = accl[i].x + bias.x;
        o.y = accl[i].y + bias.y;
        o.z = acch[i].x + bias.z;
        o.w = acch[i].y + bias.w;
        ((float4*)outp)[(mBase + ty * 2 + i) * (DD / 4) + (nBase >> 2) + tx] = o;
    }
}

// ---------------------------------------------------------------------------
// Kernel 2: o[b,n,m] = sum_d gelu(xp[b,n,d] + yp[b,m,d]) * W2[d] + b2
// R16 = R15's ONE-BARRIER cross, byte-identical, now UNBUNDLED from the proj
// change that masked its measurement (R15 total-arithmetic suggests ~45 us).
// Design: LDS's only irreplaceable job is deduplicating the y-scatter
// (R13: per-lane y from global = 97 us). Full y-panel = 32 rows x 256 d =
// 32 KB -> stage ONCE, single buffer, ONE barrier; x rows read directly
// from global (2 addrs/wave broadcast, block x-tile 32 KB = L1-resident);
// W2 via s_load. Per c4: 1 ds_read_b128 + 2 broadcast loads for 4 evals;
// 80 cyc VALU per iter >> L1 latency; 4 blocks/CU (LDS 33280 B) = 32
// waves/CU TLP. No chunk loop, no write drains, no dbuf.
// Per-thread math and summation order BIT-IDENTICAL to R12 -> absmax
// must stay 0.00390625.
// TRIPWIRE: dur >= 52 => one-barrier not a win => revert cross to R12,
// declare near-roofline (busy ~36 us vs 34 us VALU-issue floor).
// ---------------------------------------------------------------------------
#define GC1  0.79687960f
#define GC3  (-0.13053245f)
#define GC5  0.018104800f
#define GC7  (-0.0017319756f)
#define GC9  1.05671e-4f
#define GC11 (-3.64829e-6f)
#define GC13 5.37117e-8f

__global__ __launch_bounds__(512, 4) void cross_kernel(
    const float* __restrict__ xp, const float* __restrict__ yp,
    const float* __restrict__ W2, const float* __restrict__ b2,
    float* __restrict__ o)
{
    __shared__ float ys[32 * 260];   // 32 m-rows x full 256 d, stride 260

    const int tid   = threadIdx.x;
    const int b     = blockIdx.z;
    const int mBase = blockIdx.x * 32;
    const int nBase = blockIdx.y * 32;
    const int tx = tid & 31;       // m col (single)
    const int ty = tid >> 5;       // 0..15: n rows ty, ty+16

    const float4* __restrict__ xr0p =
        (const float4*)xp + (size_t)(b * N1 + nBase + ty) * (DD / 4);
    const float4* __restrict__ xr1p = xr0p + 16 * (DD / 4);
    const float4* __restrict__ yp4 =
        (const float4*)yp + (size_t)(b * N2 + mBase) * (DD / 4);
    const float4* __restrict__ W2v = (const float4*)W2;

    // stage the full 256-d y-panel once: 32 rows x 64 f4, 4 f4/thread
    const int sr = tid >> 4;            // 0..31  row
    const int sc = tid & 15;            // 0..15  f4 col (and +16,+32,+48)

    float4 py0 = yp4[sr * 64 + sc];
    float4 py1 = yp4[sr * 64 + sc + 16];
    float4 py2 = yp4[sr * 64 + sc + 32];
    float4 py3 = yp4[sr * 64 + sc + 48];
    *(float4*)&ys[sr * 260 + sc * 4]        = py0;
    *(float4*)&ys[sr * 260 + (sc + 16) * 4] = py1;
    *(float4*)&ys[sr * 260 + (sc + 32) * 4] = py2;
    *(float4*)&ys[sr * 260 + (sc + 48) * 4] = py3;
    __syncthreads();                     // the ONLY barrier

    f2 accA[2] = {};   // lo-half accumulators (i = n-row 0/1)
    f2 accB[2] = {};   // hi-half accumulators

    #pragma unroll 16
    for (int c4 = 0; c4 < 64; ++c4) {
        float4 wv  = W2v[c4];           // uniform -> s_load
        f2 wlo = {wv.x, wv.y};
        f2 whi = {wv.z, wv.w};
        float4 yr  = *(const float4*)&ys[tx * 260 + c4 * 4];
        f2 ylo = {yr.x, yr.y};
        f2 yhi = {yr.z, yr.w};
        float4 xr0 = xr0p[c4];          // 2 addrs/wave: broadcast, L1-hit
        float4 xr1 = xr1p[c4];
        #pragma unroll
        for (int i = 0; i < 2; ++i) {
            float4 xr = i ? xr1 : xr0;
            f2 xlo = {xr.x, xr.y};
            f2 xhi = {xr.z, xr.w};
            f2 hlo = xlo + ylo;
            f2 hhi = xhi + yhi;
            f2 ulo = hlo * hlo;
            f2 uhi = hhi * hhi;
            // q = Q(u): erf(h/sqrt2) = h*Q(h^2), Horner deg-6 in u
            f2 qlo = __builtin_elementwise_fma(ulo, (f2)GC13, (f2)GC11);
            f2 qhi = __builtin_elementwise_fma(uhi, (f2)GC13, (f2)GC11);
            qlo = __builtin_elementwise_fma(qlo, ulo, (f2)GC9);
            qhi = __builtin_elementwise_fma(qhi, uhi, (f2)GC9);
            qlo = __builtin_elementwise_fma(qlo, ulo, (f2)GC7);
            qhi = __builtin_elementwise_fma(qhi, uhi, (f2)GC7);
            qlo = __builtin_elementwise_fma(qlo, ulo, (f2)GC5);
            qhi = __builtin_elementwise_fma(qhi, uhi, (f2)GC5);
            qlo = __builtin_elementwise_fma(qlo, ulo, (f2)GC3);
            qhi = __builtin_elementwise_fma(qhi, uhi, (f2)GC3);
            qlo = __builtin_elementwise_fma(qlo, ulo, (f2)GC1);
            qhi = __builtin_elementwise_fma(qhi, uhi, (f2)GC1);
            // gelu = 0.5*(h + u*q); the 0.5 is applied in the epilogue
            f2 slo = __builtin_elementwise_fma(ulo, qlo, hlo);
            f2 shi = __builtin_elementwise_fma(uhi, qhi, hhi);
            accA[i] = __builtin_elementwise_fma(slo, wlo, accA[i]);
            accB[i] = __builtin_elementwise_fma(shi, whi, accB[i]);
        }
    }

    const float bias2 = b2[0];
    const size_t base = ((size_t)(b * N1 + nBase)) * N2 + mBase;
    #pragma unroll
    for (int i = 0; i < 2; ++i) {
        o[base + (size_t)(ty + 16 * i) * N2 + tx] =
            0.5f * (accA[i].x + accA[i].y + accB[i].x + accB[i].y) + bias2;
    }
}

extern "C" void kernel_launch(void* const* d_in, const int* in_sizes, int n_in,
                              void* d_out, int out_size, void* d_ws, size_t ws_size,
                              hipStream_t stream)
{
    const float* x  = (const float*)d_in[0];
    const float* y  = (const float*)d_in[1];
    const float* W1 = (const float*)d_in[2];
    const float* b1 = (const float*)d_in[3];
    const float* W2 = (const float*)d_in[4];
    const float* b2 = (const float*)d_in[5];
    float* o  = (float*)d_out;
    float* xp = (float*)d_ws;                 // 2048*256 floats = 2 MB
    float* yp = xp + (BB * N1) * DD;          // next 2 MB

    dim3 g1(64, 4, 2);               // (M/32, N/64, which) = 512 blocks
    proj_kernel<<<g1, 256, 0, stream>>>(x, y, W1, b1, xp, yp);

    dim3 g2(N2 / 32, N1 / 32, BB);   // 16 x 16 x 4 = 1024 eight-wave blocks
    cross_kernel<<<g2, 512, 0, stream>>>(xp, yp, W2, b2, o);
}

// Round 17
// 128.669 us; speedup vs baseline: 8.0489x; 1.0031x over previous
//
#include <hip/hip_runtime.h>

#define DD 256   // feature dim
#define N1 512
#define N2 512
#define BB 4

// Packed fp32: gfx950 (gfx90a+) PackedFP32Ops; the compiler selects
// v_pk_{add,mul,fma}_f32 from <2 x float> vector IR.
typedef float f2 __attribute__((ext_vector_type(2)));

// ---------------------------------------------------------------------------
// Kernel 1: projection GEMMs. R2 version VERBATIM and FROZEN (R15's rewrite
// exploded: VGPR 256, 1.08 GB scratch, 940 us). 32x64 tile / 256 threads /
// 2x4 packed register blocking, K-chunks of 32, register-prefetch double
// buffering, 512 blocks = 2/CU. Do not touch.
// ---------------------------------------------------------------------------
__global__ __launch_bounds__(256) void proj_kernel(
    const float* __restrict__ x, const float* __restrict__ y,
    const float* __restrict__ W1, const float* __restrict__ b1,
    float* __restrict__ xp, float* __restrict__ yp)
{
    const int which = blockIdx.z;
    const float* __restrict__ A  = which ? y : x;
    const float* __restrict__ Bw = W1 + which * DD * DD;
    float* __restrict__ outp = which ? yp : xp;

    __shared__ float As[32 * 36];   // As[k][m] (transposed), stride 36
    __shared__ float Bs[32 * 68];   // Bs[k][n], stride 68

    const int tid = threadIdx.x;
    const int tx = tid & 15, ty = tid >> 4;
    const int mBase = blockIdx.x * 32;
    const int nBase = blockIdx.y * 64;

    const float4* A4 = (const float4*)A;
    const float4* B4 = (const float4*)Bw;

    const int ar = tid >> 3;       // 0..31  A row (m)
    const int ac = tid & 7;        // 0..7   A float4 col (k/4)
    const int br = tid >> 4;       // 0..15  B k-row (and +16)
    const int bc = tid & 15;       // 0..15  B float4 col (n/4)

    float4 pa, pb0, pb1;
    pa  = A4[(mBase + ar) * 64 + 0 * 8 + ac];
    pb0 = B4[(0 * 32 + br) * 64 + (nBase >> 2) + bc];
    pb1 = B4[(0 * 32 + br + 16) * 64 + (nBase >> 2) + bc];

    // acc[i] split into lo/hi f2 halves of the 4-wide n block -> v_pk_fma
    f2 accl[2] = {}, acch[2] = {};

    for (int kc = 0; kc < 8; ++kc) {
        __syncthreads();
        {
            float av[4] = {pa.x, pa.y, pa.z, pa.w};
            #pragma unroll
            for (int q = 0; q < 4; ++q) As[(ac * 4 + q) * 36 + ar] = av[q];
            *(float4*)&Bs[br * 68 + bc * 4] = pb0;
            *(float4*)&Bs[(br + 16) * 68 + bc * 4] = pb1;
        }
        __syncthreads();
        if (kc < 7) {
            pa  = A4[(mBase + ar) * 64 + (kc + 1) * 8 + ac];
            pb0 = B4[((kc + 1) * 32 + br) * 64 + (nBase >> 2) + bc];
            pb1 = B4[((kc + 1) * 32 + br + 16) * 64 + (nBase >> 2) + bc];
        }
        #pragma unroll
        for (int k = 0; k < 32; ++k) {
            f2 a = *(const f2*)&As[k * 36 + ty * 2];
            float4 b = *(const float4*)&Bs[k * 68 + tx * 4];
            f2 blo = {b.x, b.y};
            f2 bhi = {b.z, b.w};
            f2 a0 = {a.x, a.x};     // splat -> op_sel, free in VOP3P
            f2 a1 = {a.y, a.y};
            accl[0] = __builtin_elementwise_fma(a0, blo, accl[0]);
            acch[0] = __builtin_elementwise_fma(a0, bhi, acch[0]);
            accl[1] = __builtin_elementwise_fma(a1, blo, accl[1]);
            acch[1] = __builtin_elementwise_fma(a1, bhi, acch[1]);
        }
    }

    float4 bias = make_float4(0.f, 0.f, 0.f, 0.f);
    if (which == 0) bias = *((const float4*)b1 + (nBase >> 2) + tx);
    #pragma unroll
    for (int i = 0; i < 2; ++i) {
        float4 o;
        o.x = accl[i].x + bias.x;
        o.y = accl[i].y + bias.y;
        o.z = acch[i].x + bias.z;
        o.w = acch[i].y + bias.w;
        ((float4*)outp)[(mBase + ty * 2 + i) * (DD / 4) + (nBase >> 2) + tx] = o;
    }
}

// ---------------------------------------------------------------------------
// Kernel 2: o[b,n,m] = sum_d gelu(xp[b,n,d] + yp[b,m,d]) * W2[d] + b2
// R17: the UNCONFOUNDED one-barrier test. R16 (58 us) bundled barriers 5->1
// WITH x moving LDS->global; VALUBusy dropped 69->62 => the x-path stall,
// not the barrier change, likely caused the loss. Here: stage BOTH panels
// ONCE (x-panel 32x256 + y-panel 32x256 = 66560 B with stride-260 pad),
// ONE barrier, then a pure 64-iter loop with the EXACT R12 read pattern
// (yr per-lane b128, xr broadcast b128, W2 s_load). Only deltas vs R12
// (52.2 us): barriers 5->1, occupancy 32->16 waves/CU (2 blocks/CU; R14
// showed 16 waves/CU is neutral for this body).
// Per-thread math and summation order BIT-IDENTICAL to R12 -> absmax must
// stay 0.00390625. Static single buffers only (R1/R9 rule).
// DECISION RULE: >=55 => revert to R12 next round, declare roofline
// (busy 36 us vs 34 us VALU-issue floor); 45-48 => barrier rhythm was
// the idle, ship.
// ---------------------------------------------------------------------------
#define GC1  0.79687960f
#define GC3  (-0.13053245f)
#define GC5  0.018104800f
#define GC7  (-0.0017319756f)
#define GC9  1.05671e-4f
#define GC11 (-3.64829e-6f)
#define GC13 5.37117e-8f

__global__ __launch_bounds__(512, 4) void cross_kernel(
    const float* __restrict__ xp, const float* __restrict__ yp,
    const float* __restrict__ W2, const float* __restrict__ b2,
    float* __restrict__ o)
{
    __shared__ float xs[32 * 260];   // 32 n-rows x full 256 d, stride 260
    __shared__ float ys[32 * 260];   // 32 m-rows x full 256 d, stride 260

    const int tid   = threadIdx.x;
    const int b     = blockIdx.z;
    const int mBase = blockIdx.x * 32;
    const int nBase = blockIdx.y * 32;
    const int tx = tid & 31;       // m col (single)
    const int ty = tid >> 5;       // 0..15: n rows ty, ty+16

    const float4* __restrict__ xp4 =
        (const float4*)xp + (size_t)(b * N1 + nBase) * (DD / 4);
    const float4* __restrict__ yp4 =
        (const float4*)yp + (size_t)(b * N2 + mBase) * (DD / 4);
    const float4* __restrict__ W2v = (const float4*)W2;

    // stage both full 256-d panels once: 32 rows x 64 f4 each, 4 f4/thread
    const int sr = tid >> 4;            // 0..31  row
    const int sc = tid & 15;            // 0..15  f4 col (and +16,+32,+48)

    float4 ax0 = xp4[sr * 64 + sc];
    float4 ax1 = xp4[sr * 64 + sc + 16];
    float4 ax2 = xp4[sr * 64 + sc + 32];
    float4 ax3 = xp4[sr * 64 + sc + 48];
    float4 ay0 = yp4[sr * 64 + sc];
    float4 ay1 = yp4[sr * 64 + sc + 16];
    float4 ay2 = yp4[sr * 64 + sc + 32];
    float4 ay3 = yp4[sr * 64 + sc + 48];
    *(float4*)&xs[sr * 260 + sc * 4]        = ax0;
    *(float4*)&xs[sr * 260 + (sc + 16) * 4] = ax1;
    *(float4*)&xs[sr * 260 + (sc + 32) * 4] = ax2;
    *(float4*)&xs[sr * 260 + (sc + 48) * 4] = ax3;
    *(float4*)&ys[sr * 260 + sc * 4]        = ay0;
    *(float4*)&ys[sr * 260 + (sc + 16) * 4] = ay1;
    *(float4*)&ys[sr * 260 + (sc + 32) * 4] = ay2;
    *(float4*)&ys[sr * 260 + (sc + 48) * 4] = ay3;
    __syncthreads();                     // the ONLY barrier

    f2 accA[2] = {};   // lo-half accumulators (i = n-row 0/1)
    f2 accB[2] = {};   // hi-half accumulators

    #pragma unroll 16
    for (int c4 = 0; c4 < 64; ++c4) {
        float4 wv  = W2v[c4];           // uniform -> s_load
        f2 wlo = {wv.x, wv.y};
        f2 whi = {wv.z, wv.w};
        float4 yr  = *(const float4*)&ys[tx * 260 + c4 * 4];
        f2 ylo = {yr.x, yr.y};
        f2 yhi = {yr.z, yr.w};
        float4 xr0 = *(const float4*)&xs[ty * 260 + c4 * 4];
        float4 xr1 = *(const float4*)&xs[(ty + 16) * 260 + c4 * 4];
        #pragma unroll
        for (int i = 0; i < 2; ++i) {
            float4 xr = i ? xr1 : xr0;
            f2 xlo = {xr.x, xr.y};
            f2 xhi = {xr.z, xr.w};
            f2 hlo = xlo + ylo;
            f2 hhi = xhi + yhi;
            f2 ulo = hlo * hlo;
            f2 uhi = hhi * hhi;
            // q = Q(u): erf(h/sqrt2) = h*Q(h^2), Horner deg-6 in u
            f2 qlo = __builtin_elementwise_fma(ulo, (f2)GC13, (f2)GC11);
            f2 qhi = __builtin_elementwise_fma(uhi, (f2)GC13, (f2)GC11);
            qlo = __builtin_elementwise_fma(qlo, ulo, (f2)GC9);
            qhi = __builtin_elementwise_fma(qhi, uhi, (f2)GC9);
            qlo = __builtin_elementwise_fma(qlo, ulo, (f2)GC7);
            qhi = __builtin_elementwise_fma(qhi, uhi, (f2)GC7);
            qlo = __builtin_elementwise_fma(qlo, ulo, (f2)GC5);
            qhi = __builtin_elementwise_fma(qhi, uhi, (f2)GC5);
            qlo = __builtin_elementwise_fma(qlo, ulo, (f2)GC3);
            qhi = __builtin_elementwise_fma(qhi, uhi, (f2)GC3);
            qlo = __builtin_elementwise_fma(qlo, ulo, (f2)GC1);
            qhi = __builtin_elementwise_fma(qhi, uhi, (f2)GC1);
            // gelu = 0.5*(h + u*q); the 0.5 is applied in the epilogue
            f2 slo = __builtin_elementwise_fma(ulo, qlo, hlo);
            f2 shi = __builtin_elementwise_fma(uhi, qhi, hhi);
            accA[i] = __builtin_elementwise_fma(slo, wlo, accA[i]);
            accB[i] = __builtin_elementwise_fma(shi, whi, accB[i]);
        }
    }

    const float bias2 = b2[0];
    const size_t base = ((size_t)(b * N1 + nBase)) * N2 + mBase;
    #pragma unroll
    for (int i = 0; i < 2; ++i) {
        o[base + (size_t)(ty + 16 * i) * N2 + tx] =
            0.5f * (accA[i].x + accA[i].y + accB[i].x + accB[i].y) + bias2;
    }
}

extern "C" void kernel_launch(void* const* d_in, const int* in_sizes, int n_in,
                              void* d_out, int out_size, void* d_ws, size_t ws_size,
                              hipStream_t stream)
{
    const float* x  = (const float*)d_in[0];
    const float* y  = (const float*)d_in[1];
    const float* W1 = (const float*)d_in[2];
    const float* b1 = (const float*)d_in[3];
    const float* W2 = (const float*)d_in[4];
    const float* b2 = (const float*)d_in[5];
    float* o  = (float*)d_out;
    float* xp = (float*)d_ws;                 // 2048*256 floats = 2 MB
    float* yp = xp + (BB * N1) * DD;          // next 2 MB

    dim3 g1(64, 4, 2);               // (M/32, N/64, which) = 512 blocks
    proj_kernel<<<g1, 256, 0, stream>>>(x, y, W1, b1, xp, yp);

    dim3 g2(N2 / 32, N1 / 32, BB);   // 16 x 16 x 4 = 1024 eight-wave blocks
    cross_kernel<<<g2, 512, 0, stream>>>(xp, yp, W2, b2, o);
}

// Round 18
// 128.127 us; speedup vs baseline: 8.0830x; 1.0042x over previous
//
#include <hip/hip_runtime.h>

#define DD 256   // feature dim
#define N1 512
#define N2 512
#define BB 4

// Packed fp32: gfx950 (gfx90a+) PackedFP32Ops; the compiler selects
// v_pk_{add,mul,fma}_f32 from <2 x float> vector IR.
typedef float f2 __attribute__((ext_vector_type(2)));

// ---------------------------------------------------------------------------
// Kernel 1: projection GEMMs. R2 version VERBATIM and FROZEN. 32x64 tile /
// 256 threads / 2x4 packed register blocking, K-chunks of 32, register-
// prefetch double buffering, 512 blocks = 2/CU.
// (R15's macro-unrolled rewrite exploded: VGPR 256, 1.08 GB scratch. Loop
// form is the proven shape; never touch proj.)
// ---------------------------------------------------------------------------
__global__ __launch_bounds__(256) void proj_kernel(
    const float* __restrict__ x, const float* __restrict__ y,
    const float* __restrict__ W1, const float* __restrict__ b1,
    float* __restrict__ xp, float* __restrict__ yp)
{
    const int which = blockIdx.z;
    const float* __restrict__ A  = which ? y : x;
    const float* __restrict__ Bw = W1 + which * DD * DD;
    float* __restrict__ outp = which ? yp : xp;

    __shared__ float As[32 * 36];   // As[k][m] (transposed), stride 36
    __shared__ float Bs[32 * 68];   // Bs[k][n], stride 68

    const int tid = threadIdx.x;
    const int tx = tid & 15, ty = tid >> 4;
    const int mBase = blockIdx.x * 32;
    const int nBase = blockIdx.y * 64;

    const float4* A4 = (const float4*)A;
    const float4* B4 = (const float4*)Bw;

    const int ar = tid >> 3;       // 0..31  A row (m)
    const int ac = tid & 7;        // 0..7   A float4 col (k/4)
    const int br = tid >> 4;       // 0..15  B k-row (and +16)
    const int bc = tid & 15;       // 0..15  B float4 col (n/4)

    float4 pa, pb0, pb1;
    pa  = A4[(mBase + ar) * 64 + 0 * 8 + ac];
    pb0 = B4[(0 * 32 + br) * 64 + (nBase >> 2) + bc];
    pb1 = B4[(0 * 32 + br + 16) * 64 + (nBase >> 2) + bc];

    // acc[i] split into lo/hi f2 halves of the 4-wide n block -> v_pk_fma
    f2 accl[2] = {}, acch[2] = {};

    for (int kc = 0; kc < 8; ++kc) {
        __syncthreads();
        {
            float av[4] = {pa.x, pa.y, pa.z, pa.w};
            #pragma unroll
            for (int q = 0; q < 4; ++q) As[(ac * 4 + q) * 36 + ar] = av[q];
            *(float4*)&Bs[br * 68 + bc * 4] = pb0;
            *(float4*)&Bs[(br + 16) * 68 + bc * 4] = pb1;
        }
        __syncthreads();
        if (kc < 7) {
            pa  = A4[(mBase + ar) * 64 + (kc + 1) * 8 + ac];
            pb0 = B4[((kc + 1) * 32 + br) * 64 + (nBase >> 2) + bc];
            pb1 = B4[((kc + 1) * 32 + br + 16) * 64 + (nBase >> 2) + bc];
        }
        #pragma unroll
        for (int k = 0; k < 32; ++k) {
            f2 a = *(const f2*)&As[k * 36 + ty * 2];
            float4 b = *(const float4*)&Bs[k * 68 + tx * 4];
            f2 blo = {b.x, b.y};
            f2 bhi = {b.z, b.w};
            f2 a0 = {a.x, a.x};     // splat -> op_sel, free in VOP3P
            f2 a1 = {a.y, a.y};
            accl[0] = __builtin_elementwise_fma(a0, blo, accl[0]);
            acch[0] = __builtin_elementwise_fma(a0, bhi, acch[0]);
            accl[1] = __builtin_elementwise_fma(a1, blo, accl[1]);
            acch[1] = __builtin_elementwise_fma(a1, bhi, acch[1]);
        }
    }

    float4 bias = make_float4(0.f, 0.f, 0.f, 0.f);
    if (which == 0) bias = *((const float4*)b1 + (nBase >> 2) + tx);
    #pragma unroll
    for (int i = 0; i < 2; ++i) {
        float4 o;
        o.x = accl[i].x + bias.x;
        o.y = accl[i].y + bias.y;
        o.z = acch[i].x + bias.z;
        o.w = acch[i].y + bias.w;
        ((float4*)outp)[(mBase + ty * 2 + i) * (DD / 4) + (nBase >> 2) + tx] = o;
    }
}

// ---------------------------------------------------------------------------
// Kernel 2: o[b,n,m] = sum_d gelu(xp[b,n,d] + yp[b,m,d]) * W2[d] + b2
// FINAL = R12 verbatim (best measured: 52.2 us, VALUBusy 69%, occ 50%).
// 512-thread blocks, 32n x 32m tile, 2 outputs/thread, 1024 blocks =
// exactly 4 blocks/CU (LDS 34816 x 4 = 139 KB), 32 waves/CU, zero tail.
// Static-NAMED LDS double-buffer (5 barriers) -- runtime-indexed dbuf is
// condemned (R1/R9: rule-#20 scratch catastrophe).
// Gelu: trans-free deg-13 odd Chebyshev erf polynomial (closed-form Bessel
// coefficients), 0.5 folded once into the epilogue.
//
// Design space exhausted (R0-R17): gelu form (trans/paired-rcp/poly),
// barriers (8/5/4/1), chunk (64/128), blocking (1x2/2x2), occupancy
// (2-8 blk/CU), grid fit, LDS policy (full/y-only/none). Busy ~36 us vs
// ~34 us VALU-issue floor (10 pk-ops x 4 cyc per f2 across 1024 SIMDs);
// every variant targeting the ~16 us structural idle regressed or was
// neutral. This config is the empirical optimum.
// ---------------------------------------------------------------------------
#define GC1  0.79687960f
#define GC3  (-0.13053245f)
#define GC5  0.018104800f
#define GC7  (-0.0017319756f)
#define GC9  1.05671e-4f
#define GC11 (-3.64829e-6f)
#define GC13 5.37117e-8f

__global__ __launch_bounds__(512, 4) void cross_kernel(
    const float* __restrict__ xp, const float* __restrict__ yp,
    const float* __restrict__ W2, const float* __restrict__ b2,
    float* __restrict__ o)
{
    __shared__ float xsA[32 * 68];
    __shared__ float xsB[32 * 68];
    __shared__ float ysA[32 * 68];
    __shared__ float ysB[32 * 68];

    const int tid   = threadIdx.x;
    const int b     = blockIdx.z;
    const int mBase = blockIdx.x * 32;
    const int nBase = blockIdx.y * 32;
    const int tx = tid & 31;       // m col (single)
    const int ty = tid >> 5;       // 0..15: n rows ty, ty+16

    const float4* xp4 = (const float4*)xp + (b * N1 + nBase) * (DD / 4);
    const float4* yp4 = (const float4*)yp + (b * N2 + mBase) * (DD / 4);
    const float4* __restrict__ W2v = (const float4*)W2;

    // staging per 64-d chunk: xs,ys = 32 rows x 16 f4, 1 f4/thread each
    const int sr = tid >> 4;            // 0..31  row
    const int sc = tid & 15;            // 0..15  f4 col within chunk

    float4 px0, py0;
    f2 accA[2] = {};   // lo-half accumulators
    f2 accB[2] = {};   // hi-half accumulators

#define STAGE_LOAD(CH)                                      \
    px0 = xp4[sr * 64 + (CH) * 16 + sc];                    \
    py0 = yp4[sr * 64 + (CH) * 16 + sc];

#define STAGE_WRITE(XS, YS)                                 \
    *(float4*)&XS[sr * 68 + sc * 4] = px0;                  \
    *(float4*)&YS[sr * 68 + sc * 4] = py0;

#define COMPUTE(XS, YS, KC)                                                    \
    _Pragma("unroll")                                                          \
    for (int c4 = 0; c4 < 16; ++c4) {                                          \
        float4 wv = W2v[(KC) * 16 + c4];                                       \
        f2 wlo = {wv.x, wv.y};                                                 \
        f2 whi = {wv.z, wv.w};                                                 \
        float4 yr = *(const float4*)&YS[tx * 68 + c4 * 4];                     \
        f2 ylo = {yr.x, yr.y};                                                 \
        f2 yhi = {yr.z, yr.w};                                                 \
        _Pragma("unroll")                                                      \
        for (int i = 0; i < 2; ++i) {                                          \
            float4 xr = *(const float4*)&XS[(ty + 16 * i) * 68 + c4 * 4];      \
            f2 xlo = {xr.x, xr.y};                                             \
            f2 xhi = {xr.z, xr.w};                                             \
            f2 hlo = xlo + ylo;                                                \
            f2 hhi = xhi + yhi;                                                \
            f2 ulo = hlo * hlo;                                                \
            f2 uhi = hhi * hhi;                                                \
            f2 qlo = __builtin_elementwise_fma(ulo, (f2)GC13, (f2)GC11);       \
            f2 qhi = __builtin_elementwise_fma(uhi, (f2)GC13, (f2)GC11);       \
            qlo = __builtin_elementwise_fma(qlo, ulo, (f2)GC9);                \
            qhi = __builtin_elementwise_fma(qhi, uhi, (f2)GC9);                \
            qlo = __builtin_elementwise_fma(qlo, ulo, (f2)GC7);                \
            qhi = __builtin_elementwise_fma(qhi, uhi, (f2)GC7);                \
            qlo = __builtin_elementwise_fma(qlo, ulo, (f2)GC5);                \
            qhi = __builtin_elementwise_fma(qhi, uhi, (f2)GC5);                \
            qlo = __builtin_elementwise_fma(qlo, ulo, (f2)GC3);                \
            qhi = __builtin_elementwise_fma(qhi, uhi, (f2)GC3);                \
            qlo = __builtin_elementwise_fma(qlo, ulo, (f2)GC1);                \
            qhi = __builtin_elementwise_fma(qhi, uhi, (f2)GC1);                \
            f2 slo = __builtin_elementwise_fma(ulo, qlo, hlo);                 \
            f2 shi = __builtin_elementwise_fma(uhi, qhi, hhi);                 \
            accA[i] = __builtin_elementwise_fma(slo, wlo, accA[i]);            \
            accB[i] = __builtin_elementwise_fma(shi, whi, accB[i]);            \
        }                                                                      \
    }

    STAGE_LOAD(0)
    STAGE_WRITE(xsA, ysA)
    __syncthreads();                    // B0: bufA(chunk0) ready

    STAGE_LOAD(1)                       // global latency hides under compute
    COMPUTE(xsA, ysA, 0)
    STAGE_WRITE(xsB, ysB)
    __syncthreads();                    // B1: bufB(chunk1) ready, bufA free

    STAGE_LOAD(2)
    COMPUTE(xsB, ysB, 1)
    STAGE_WRITE(xsA, ysA)
    __syncthreads();                    // B2: bufA(chunk2) ready, bufB free

    STAGE_LOAD(3)
    COMPUTE(xsA, ysA, 2)
    STAGE_WRITE(xsB, ysB)
    __syncthreads();                    // B3: bufB(chunk3) ready

    COMPUTE(xsB, ysB, 3)

#undef STAGE_LOAD
#undef STAGE_WRITE
#undef COMPUTE

    const float bias2 = b2[0];
    const size_t base = ((size_t)(b * N1 + nBase)) * N2 + mBase;
    #pragma unroll
    for (int i = 0; i < 2; ++i) {
        o[base + (size_t)(ty + 16 * i) * N2 + tx] =
            0.5f * (accA[i].x + accA[i].y + accB[i].x + accB[i].y) + bias2;
    }
}

extern "C" void kernel_launch(void* const* d_in, const int* in_sizes, int n_in,
                              void* d_out, int out_size, void* d_ws, size_t ws_size,
                              hipStream_t stream)
{
    const float* x  = (const float*)d_in[0];
    const float* y  = (const float*)d_in[1];
    const float* W1 = (const float*)d_in[2];
    const float* b1 = (const float*)d_in[3];
    const float* W2 = (const float*)d_in[4];
    const float* b2 = (const float*)d_in[5];
    float* o  = (float*)d_out;
    float* xp = (float*)d_ws;                 // 2048*256 floats = 2 MB
    float* yp = xp + (BB * N1) * DD;          // next 2 MB

    dim3 g1(64, 4, 2);               // (M/32, N/64, which) = 512 blocks
    proj_kernel<<<g1, 256, 0, stream>>>(x, y, W1, b1, xp, yp);

    dim3 g2(N2 / 32, N1 / 32, BB);   // 16 x 16 x 4 = 1024 eight-wave blocks
    cross_kernel<<<g2, 512, 0, stream>>>(xp, yp, W2, b2, o);
}